// Round 15
// baseline (182.060 us; speedup 1.0000x reference)
//
#include <hip/hip_runtime.h>

typedef _Float16 f16;
typedef __attribute__((ext_vector_type(4))) _Float16 half4;
typedef __attribute__((ext_vector_type(8))) _Float16 half8;
typedef __attribute__((ext_vector_type(4))) float v4f;
typedef __attribute__((ext_vector_type(4))) float f32x4v;
typedef __attribute__((ext_vector_type(4))) int i32x4;
typedef __attribute__((ext_vector_type(8))) unsigned short u16x8;

#define NEG_BIG -1e30f

#define MFMA32(a, b, c) __builtin_amdgcn_mfma_f32_16x16x32_f16(a, b, c, 0, 0, 0)
#if __has_builtin(__builtin_amdgcn_mfma_f32_16x16x16_f16)
#define MFMA16(a, b, c) __builtin_amdgcn_mfma_f32_16x16x16_f16(a, b, c, 0, 0, 0)
#else
#define MFMA16(a, b, c) __builtin_amdgcn_mfma_f32_16x16x16f16(a, b, c, 0, 0, 0)
#endif

// ---------------------------------------------------------------------------
// Kernel 1: convert queries/keys/values f32 -> f16 (2M elems each)
// ---------------------------------------------------------------------------
__global__ __launch_bounds__(256) void cvt3_kernel(
    const float* __restrict__ q, const float* __restrict__ k, const float* __restrict__ v,
    f16* __restrict__ oq, f16* __restrict__ ok, f16* __restrict__ ov)
{
    int gid = blockIdx.x * 256 + threadIdx.x;
    int seg = gid >> 19;
    int off = (gid & 524287) << 2;
    const float* src = (seg == 0) ? q : (seg == 1) ? k : v;
    f16* dst = (seg == 0) ? oq : (seg == 1) ? ok : ov;
    f32x4v x = *(const f32x4v*)(src + off);
    union { f16 h[4]; unsigned long long u; } pk;
    pk.h[0] = (f16)x[0]; pk.h[1] = (f16)x[1]; pk.h[2] = (f16)x[2]; pk.h[3] = (f16)x[3];
    *(unsigned long long*)(dst + off) = pk.u;
}

// ---------------------------------------------------------------------------
// Kernel 2: W (1024x1024 f32 row-major) -> W^T (1024x1024 f16 row-major)
// ---------------------------------------------------------------------------
__global__ __launch_bounds__(256) void wtrans_kernel(
    const float* __restrict__ w0, const float* __restrict__ w1,
    const float* __restrict__ w2, const float* __restrict__ w3,
    f16* __restrict__ o0, f16* __restrict__ o1, f16* __restrict__ o2, f16* __restrict__ o3)
{
    __shared__ f16 tile[64][72];
    int zs = blockIdx.z;
    const float* W = (zs == 0) ? w0 : (zs == 1) ? w1 : (zs == 2) ? w2 : w3;
    f16* O = (zs == 0) ? o0 : (zs == 1) ? o1 : (zs == 2) ? o2 : o3;
    int cx = blockIdx.x * 64;
    int ry = blockIdx.y * 64;
    int tid = threadIdx.x;
    #pragma unroll
    for (int p = 0; p < 4; ++p) {
        int idx = tid + p * 256;
        int r = idx >> 4, c4 = (idx & 15) << 2;
        f32x4v x = *(const f32x4v*)&W[(size_t)(ry + r) * 1024 + cx + c4];
        tile[r][c4 + 0] = (f16)x[0]; tile[r][c4 + 1] = (f16)x[1];
        tile[r][c4 + 2] = (f16)x[2]; tile[r][c4 + 3] = (f16)x[3];
    }
    __syncthreads();
    #pragma unroll
    for (int p = 0; p < 2; ++p) {
        int idx = tid + p * 256;
        int n = idx >> 3, c8 = (idx & 7) << 3;
        union { f16 h[8]; u16x8 u; } pk;
        #pragma unroll
        for (int j = 0; j < 8; ++j) pk.h[j] = tile[c8 + j][n];
        *(u16x8*)&O[(size_t)(cx + n) * 1024 + ry + c8] = pk.u;
    }
}

// ---------------------------------------------------------------------------
// GEMM core: C[m][n] = A[2048x1024] @ Bt[1024x1024]^T + bias[n]
// ---------------------------------------------------------------------------
__device__ __forceinline__ void gemm_core(
    const f16* __restrict__ A, const f16* __restrict__ Bt,
    const float* __restrict__ bias, void* __restrict__ out, int mode)
{
    __shared__ f16 As[128 * 72];
    __shared__ f16 Bs[64 * 72];
    const int mbase = blockIdx.y * 128;
    const int nbase = blockIdx.x * 64;
    int tid = threadIdx.x;
    int lane = tid & 63, wave = tid >> 6;
    int ln = lane & 15, hi = lane >> 4;
    int wr = wave & 1, wc = wave >> 1;
    v4f acc[4][2];
    #pragma unroll
    for (int rt = 0; rt < 4; ++rt)
        #pragma unroll
        for (int ct = 0; ct < 2; ++ct) acc[rt][ct] = (v4f){0.f, 0.f, 0.f, 0.f};

    for (int kb = 0; kb < 1024; kb += 64) {
        __syncthreads();
        #pragma unroll
        for (int p = 0; p < 4; ++p) {
            int idx = tid + p * 256;
            int r = idx >> 3, c8 = (idx & 7) << 3;
            *(u16x8*)&As[r * 72 + c8] = *(const u16x8*)&A[(size_t)(mbase + r) * 1024 + kb + c8];
        }
        #pragma unroll
        for (int p = 0; p < 2; ++p) {
            int idx = tid + p * 256;
            int r = idx >> 3, c8 = (idx & 7) << 3;
            *(u16x8*)&Bs[r * 72 + c8] = *(const u16x8*)&Bt[(size_t)(nbase + r) * 1024 + kb + c8];
        }
        __syncthreads();
        #pragma unroll
        for (int kk = 0; kk < 64; kk += 32) {
            half8 aF[4], bF[2];
            #pragma unroll
            for (int rt = 0; rt < 4; ++rt)
                aF[rt] = *(const half8*)&As[(wr * 64 + rt * 16 + ln) * 72 + kk + 8 * hi];
            #pragma unroll
            for (int ct = 0; ct < 2; ++ct)
                bF[ct] = *(const half8*)&Bs[(wc * 32 + ct * 16 + ln) * 72 + kk + 8 * hi];
            #pragma unroll
            for (int rt = 0; rt < 4; ++rt)
                #pragma unroll
                for (int ct = 0; ct < 2; ++ct)
                    acc[rt][ct] = __builtin_amdgcn_mfma_f32_16x16x32_f16(aF[rt], bF[ct], acc[rt][ct], 0, 0, 0);
        }
    }
    #pragma unroll
    for (int rt = 0; rt < 4; ++rt)
      #pragma unroll
      for (int ct = 0; ct < 2; ++ct)
        #pragma unroll
        for (int r = 0; r < 4; ++r) {
            int m = mbase + wr * 64 + rt * 16 + hi * 4 + r;
            int n = nbase + wc * 32 + ct * 16 + ln;
            float val = acc[rt][ct][r] + bias[n];
            if (mode == 0) {
                int bb = m >> 10, nq = m & 1023, hh = n >> 6, d = n & 63;
                ((f16*)out)[(((size_t)(bb * 16 + hh)) * 1024 + nq) * 64 + d] = (f16)val;
            } else if (mode == 1) {
                int bb = m >> 10, nq = m & 1023, hh = n >> 6, d = n & 63;
                ((f16*)out)[(((size_t)(bb * 16 + hh)) * 64 + d) * 1024 + nq] = (f16)val;
            } else {
                ((float*)out)[(size_t)m * 1024 + n] = val;
            }
        }
}

__global__ __launch_bounds__(256) void qkv_gemm_kernel(
    const f16* __restrict__ xq, const f16* __restrict__ xk, const f16* __restrict__ xv,
    const f16* __restrict__ wqt, const f16* __restrict__ wkt, const f16* __restrict__ wvt,
    const float* __restrict__ bq, const float* __restrict__ bk, const float* __restrict__ bv,
    f16* __restrict__ oQ, f16* __restrict__ oK, f16* __restrict__ oVt)
{
    int z = blockIdx.z;
    const f16* A  = (z == 0) ? xq  : (z == 1) ? xk  : xv;
    const f16* B  = (z == 0) ? wqt : (z == 1) ? wkt : wvt;
    const float* bi = (z == 0) ? bq : (z == 1) ? bk : bv;
    void* out = (z == 0) ? (void*)oQ : (z == 1) ? (void*)oK : (void*)oVt;
    gemm_core(A, B, bi, out, (z == 2) ? 1 : 0);
}

__global__ __launch_bounds__(256) void o_gemm_kernel(
    const f16* __restrict__ A, const f16* __restrict__ Wot,
    const float* __restrict__ bo, float* __restrict__ out)
{
    gemm_core(A, Wot, bo, out, 2);
}

// ---------------------------------------------------------------------------
// Split-K/2 flash attention, barrier-free, V reg prefetch + 3-DEEP w/m
// register prefetch (A,B,C buffers, fully unrolled 8-tile schedule so all
// buffer indices are static — rule #20). w/m issue->consume distance is now
// 3 process calls (~900 cy) ≈ HBM latency, removing the per-tile stall that
// capped R14 at 2.37 TB/s. K-half in LDS (72 KB); V via vC[16] refilled at
// the bottom of each tile (R14-proven); amap nontemporal; single barrier.
// Partial O f16 + (m,l) f32 -> merge_kernel. No min-wave bound (R8 trap).
// ---------------------------------------------------------------------------
__global__ __launch_bounds__(512) void attn_kernel(
    const f16* __restrict__ Qp, const f16* __restrict__ Kp, const f16* __restrict__ Vt,
    const float* __restrict__ weights, const int* __restrict__ mask,
    float* __restrict__ amap, f16* __restrict__ Po, float* __restrict__ Ml)
{
    __shared__ f16 Ks[512 * 72];

    int h = blockIdx.x, qc = blockIdx.y, zid = blockIdx.z;
    int b = zid >> 1, kh = zid & 1;
    int bh = b * 16 + h;
    int tid = threadIdx.x;
    int lane = tid & 63, wave = tid >> 6;
    int ln = lane & 15, hi = lane >> 4;

    const f16* Kb = Kp + ((size_t)bh * 1024 + kh * 512) * 64;   // K rows of this half
    const f16* Vb = Vt + (size_t)bh * 64 * 1024 + kh * 512;     // V^T, col offset

    // ---- stage K half: 4096 16B chunks, fully contiguous in global ----
    #pragma unroll
    for (int i = 0; i < 8; ++i) {
        int c = tid + i * 512;
        int r = c >> 3, g = c & 7;
        *(half8*)&Ks[r * 72 + g * 8] = *(const half8*)&Kb[(size_t)c * 8];
    }

    int qg = qc * 128 + wave * 16 + ln;                 // this lane's q row
    const f16*  Qb = Qp + ((size_t)bh * 1024 + qg) * 64;
    const float* Wr = weights + ((size_t)bh * 1024 + qg) * 1024 + kh * 512;
    const int*   Mr = mask    + ((size_t)bh * 1024 + qg) * 1024 + kh * 512;
    float*       Ar = amap    + ((size_t)bh * 1024 + qg) * 1024 + kh * 512;

    half8 qf0 = *(const half8*)&Qb[8 * hi];
    half8 qf1 = *(const half8*)&Qb[32 + 8 * hi];

    float mrun = -3.0e38f, lrun = 0.f;
    v4f oacc[4];
    #pragma unroll
    for (int dt = 0; dt < 4; ++dt) oacc[dt] = (v4f){0.f, 0.f, 0.f, 0.f};

    // ---- V register buffer for tile 0 (issued first: PV(0)'s wait must
    //      not drain the w/m prefetch issued below) ----
    half4 vC[16];
    #pragma unroll
    for (int t = 0; t < 4; ++t)
        #pragma unroll
        for (int dt = 0; dt < 4; ++dt)
            vC[t * 4 + dt] = *(const half4*)&Vb[(size_t)(dt * 16 + ln) * 1024 + t * 16 + 4 * hi];

    // 3-deep named prefetch of weights/mask (tiles 0,1,2)
    f32x4v wA[4], wB[4], wC[4]; i32x4 mA[4], mB[4], mC[4];
    #pragma unroll
    for (int t = 0; t < 4; ++t) {
        wA[t] = *(const f32x4v*)&Wr[t * 16 + 4 * hi];
        mA[t] = *(const i32x4*)&Mr[t * 16 + 4 * hi];
        wB[t] = *(const f32x4v*)&Wr[64 + t * 16 + 4 * hi];
        mB[t] = *(const i32x4*)&Mr[64 + t * 16 + 4 * hi];
        wC[t] = *(const f32x4v*)&Wr[128 + t * 16 + 4 * hi];
        mC[t] = *(const i32x4*)&Mr[128 + t * 16 + 4 * hi];
    }
    __syncthreads();   // K staged; read-only from here, no more barriers

    auto process = [&](int kt, const f32x4v (&wb)[4], const i32x4 (&mb)[4]) {
        // ---- S^T = K Q^T from LDS ----
        v4f st[4];
        #pragma unroll
        for (int t = 0; t < 4; ++t) {
            const f16* kr = &Ks[(kt * 64 + t * 16 + ln) * 72 + 8 * hi];
            half8 ka = *(const half8*)kr;
            half8 kc = *(const half8*)(kr + 32);
            v4f a = (v4f){0.f, 0.f, 0.f, 0.f};
            a = MFMA32(ka, qf0, a);
            a = MFMA32(kc, qf1, a);
            st[t] = a;
        }
        // ---- amap (nontemporal) + z ----
        float z[4][4];
        #pragma unroll
        for (int t = 0; t < 4; ++t) {
            f32x4v sv = st[t] * 0.125f;
            __builtin_nontemporal_store(sv, (f32x4v*)&Ar[kt * 64 + t * 16 + 4 * hi]);
            #pragma unroll
            for (int r = 0; r < 4; ++r)
                z[t][r] = (mb[t][r] == 0) ? NEG_BIG : sv[r] * wb[t][r];
        }
        // ---- online softmax (q lane-local; reduce across hi groups) ----
        float tm = z[0][0];
        #pragma unroll
        for (int t = 0; t < 4; ++t)
            #pragma unroll
            for (int r = 0; r < 4; ++r) tm = fmaxf(tm, z[t][r]);
        tm = fmaxf(tm, __shfl_xor(tm, 16, 64));
        tm = fmaxf(tm, __shfl_xor(tm, 32, 64));
        float mnew = fmaxf(mrun, tm);
        float fsc = __expf(mrun - mnew);
        float p[4][4];
        float tsum = 0.f;
        #pragma unroll
        for (int t = 0; t < 4; ++t)
            #pragma unroll
            for (int r = 0; r < 4; ++r) { p[t][r] = __expf(z[t][r] - mnew); tsum += p[t][r]; }
        tsum += __shfl_xor(tsum, 16, 64);
        tsum += __shfl_xor(tsum, 32, 64);
        lrun = lrun * fsc + tsum;
        mrun = mnew;
        #pragma unroll
        for (int dt = 0; dt < 4; ++dt) oacc[dt] *= fsc;
        // ---- P^T f16 fragments (K=16 layout k = 4*hi + j) ----
        half4 pf[4];
        #pragma unroll
        for (int t = 0; t < 4; ++t) {
            half4 v;
            v[0] = (f16)p[t][0]; v[1] = (f16)p[t][1];
            v[2] = (f16)p[t][2]; v[3] = (f16)p[t][3];
            pf[t] = v;
        }
        // ---- O^T += V^T P^T from register buffer ----
        #pragma unroll
        for (int t = 0; t < 4; ++t)
            #pragma unroll
            for (int dt = 0; dt < 4; ++dt)
                oacc[dt] = MFMA16(vC[t * 4 + dt], pf[t], oacc[dt]);
        // ---- refill vC with tile kt+1 (after consumption; L2-served) ----
        if (kt < 7) {
            #pragma unroll
            for (int t = 0; t < 4; ++t)
                #pragma unroll
                for (int dt = 0; dt < 4; ++dt)
                    vC[t * 4 + dt] = *(const half4*)&Vb[(size_t)(dt * 16 + ln) * 1024
                                                        + (kt + 1) * 64 + t * 16 + 4 * hi];
        }
    };

    auto refill = [&](f32x4v (&wb)[4], i32x4 (&mb)[4], int src) {
        #pragma unroll
        for (int t = 0; t < 4; ++t) {
            wb[t] = *(const f32x4v*)&Wr[src * 64 + t * 16 + 4 * hi];
            mb[t] = *(const i32x4*)&Mr[src * 64 + t * 16 + 4 * hi];
        }
    };

    // ---- fully unrolled 8-tile schedule, static A,B,C rotation ----
    process(0, wA, mA); refill(wA, mA, 3);
    process(1, wB, mB); refill(wB, mB, 4);
    process(2, wC, mC); refill(wC, mC, 5);
    process(3, wA, mA); refill(wA, mA, 6);
    process(4, wB, mB); refill(wB, mB, 7);
    process(5, wC, mC);
    process(6, wA, mA);
    process(7, wB, mB);

    // ---- epilogue: store unnormalized partial O (f16) + (m, l) ----
    size_t prow = ((size_t)kh * 32 + bh) * 1024 + qg;
    #pragma unroll
    for (int dt = 0; dt < 4; ++dt) {
        half4 ov;
        #pragma unroll
        for (int r = 0; r < 4; ++r) ov[r] = (f16)oacc[dt][r];
        *(half4*)&Po[prow * 64 + dt * 16 + 4 * hi] = ov;
    }
    if (hi == 0) {
        float2 ml = make_float2(mrun, lrun);
        *(float2*)&Ml[prow * 2] = ml;
    }
}

// ---------------------------------------------------------------------------
// Merge the two k-half partials: O = (w0*O0 + w1*O1) / (w0*l0 + w1*l1)
// ---------------------------------------------------------------------------
__global__ __launch_bounds__(256) void merge_kernel(
    const f16* __restrict__ Po, const float* __restrict__ Ml, f16* __restrict__ hout)
{
    int gid = blockIdx.x * 256 + threadIdx.x;
    int dq = gid & 15;
    int q  = (gid >> 4) & 1023;
    int bh = gid >> 14;
    int b = bh >> 4, h = bh & 15;
    size_t r0 = (size_t)bh * 1024 + q;
    size_t r1 = (size_t)(32 + bh) * 1024 + q;
    float2 ml0 = *(const float2*)&Ml[r0 * 2];
    float2 ml1 = *(const float2*)&Ml[r1 * 2];
    float M = fmaxf(ml0.x, ml1.x);
    float w0 = __expf(ml0.x - M), w1 = __expf(ml1.x - M);
    float rL = 1.0f / (w0 * ml0.y + w1 * ml1.y);
    half4 o0 = *(const half4*)&Po[r0 * 64 + dq * 4];
    half4 o1 = *(const half4*)&Po[r1 * 64 + dq * 4];
    half4 ov;
    #pragma unroll
    for (int j = 0; j < 4; ++j)
        ov[j] = (f16)((w0 * (float)o0[j] + w1 * (float)o1[j]) * rL);
    *(half4*)&hout[((size_t)(b * 1024 + q)) * 1024 + h * 64 + dq * 4] = ov;
}

// ---------------------------------------------------------------------------
extern "C" void kernel_launch(void* const* d_in, const int* in_sizes, int n_in,
                              void* d_out, int out_size, void* d_ws, size_t ws_size,
                              hipStream_t stream)
{
    const float* queries  = (const float*)d_in[0];
    const float* keys     = (const float*)d_in[1];
    const float* values   = (const float*)d_in[2];
    const int*   amask    = (const int*)d_in[3];
    const float* aweights = (const float*)d_in[4];
    const float* Wq = (const float*)d_in[5];  const float* bq = (const float*)d_in[6];
    const float* Wk = (const float*)d_in[7];  const float* bk = (const float*)d_in[8];
    const float* Wv = (const float*)d_in[9];  const float* bv = (const float*)d_in[10];
    const float* Wo = (const float*)d_in[11]; const float* bo = (const float*)d_in[12];

    char* ws = (char*)d_ws;
    const size_t MB = 1024 * 1024;
    f16* q_h  = (f16*)(ws + 0 * MB);
    f16* k_h  = (f16*)(ws + 4 * MB);
    f16* v_h  = (f16*)(ws + 8 * MB);
    f16* wqt  = (f16*)(ws + 12 * MB);
    f16* wkt  = (f16*)(ws + 14 * MB);
    f16* wvt  = (f16*)(ws + 16 * MB);
    f16* wot  = (f16*)(ws + 18 * MB);
    f16* Qp   = (f16*)(ws + 20 * MB);
    f16* Kp   = (f16*)(ws + 24 * MB);
    f16* Vt   = (f16*)(ws + 28 * MB);
    f16* hout = (f16*)(ws + 32 * MB);
    // Po/Ml reuse 0..17 MB (q_h/k_h/v_h/wqt/wkt dead after qkv_gemm; wot@18 safe)
    f16*   Po = (f16*)(ws + 0 * MB);       // 8 MB: 2 x 32 x 1024 x 64 f16
    float* Ml = (float*)(ws + 16 * MB);    // 512 KB: 2 x 32 x 1024 x 2 f32

    float* out_main = (float*)d_out;
    float* att_map  = out_main + (size_t)2 * 1024 * 1024;

    cvt3_kernel<<<6144, 256, 0, stream>>>(queries, keys, values, q_h, k_h, v_h);
    wtrans_kernel<<<dim3(16, 16, 4), 256, 0, stream>>>(Wq, Wk, Wv, Wo, wqt, wkt, wvt, wot);
    qkv_gemm_kernel<<<dim3(16, 16, 3), 256, 0, stream>>>(q_h, k_h, v_h, wqt, wkt, wvt,
                                                         bq, bk, bv, Qp, Kp, Vt);
    attn_kernel<<<dim3(16, 8, 4), 512, 0, stream>>>(Qp, Kp, Vt, aweights, amask,
                                                    att_map, Po, Ml);
    merge_kernel<<<2048, 256, 0, stream>>>(Po, Ml, hout);
    o_gemm_kernel<<<dim3(16, 16, 1), 256, 0, stream>>>(hout, wot, bo, out_main);
}

// Round 16
// 157.719 us; speedup vs baseline: 1.1543x; 1.1543x over previous
//
#include <hip/hip_runtime.h>

typedef _Float16 f16;
typedef __attribute__((ext_vector_type(4))) _Float16 half4;
typedef __attribute__((ext_vector_type(8))) _Float16 half8;
typedef __attribute__((ext_vector_type(4))) float v4f;
typedef __attribute__((ext_vector_type(4))) float f32x4v;
typedef __attribute__((ext_vector_type(4))) int i32x4;
typedef __attribute__((ext_vector_type(8))) unsigned short u16x8;

#define NEG_BIG -1e30f

#define MFMA32(a, b, c) __builtin_amdgcn_mfma_f32_16x16x32_f16(a, b, c, 0, 0, 0)
#if __has_builtin(__builtin_amdgcn_mfma_f32_16x16x16_f16)
#define MFMA16(a, b, c) __builtin_amdgcn_mfma_f32_16x16x16_f16(a, b, c, 0, 0, 0)
#else
#define MFMA16(a, b, c) __builtin_amdgcn_mfma_f32_16x16x16f16(a, b, c, 0, 0, 0)
#endif

// ---------------------------------------------------------------------------
// Kernel 1: convert queries/keys/values f32 -> f16 (2M elems each)
// ---------------------------------------------------------------------------
__global__ __launch_bounds__(256) void cvt3_kernel(
    const float* __restrict__ q, const float* __restrict__ k, const float* __restrict__ v,
    f16* __restrict__ oq, f16* __restrict__ ok, f16* __restrict__ ov)
{
    int gid = blockIdx.x * 256 + threadIdx.x;
    int seg = gid >> 19;
    int off = (gid & 524287) << 2;
    const float* src = (seg == 0) ? q : (seg == 1) ? k : v;
    f16* dst = (seg == 0) ? oq : (seg == 1) ? ok : ov;
    f32x4v x = *(const f32x4v*)(src + off);
    union { f16 h[4]; unsigned long long u; } pk;
    pk.h[0] = (f16)x[0]; pk.h[1] = (f16)x[1]; pk.h[2] = (f16)x[2]; pk.h[3] = (f16)x[3];
    *(unsigned long long*)(dst + off) = pk.u;
}

// ---------------------------------------------------------------------------
// Kernel 2: W (1024x1024 f32 row-major) -> W^T (1024x1024 f16 row-major)
// ---------------------------------------------------------------------------
__global__ __launch_bounds__(256) void wtrans_kernel(
    const float* __restrict__ w0, const float* __restrict__ w1,
    const float* __restrict__ w2, const float* __restrict__ w3,
    f16* __restrict__ o0, f16* __restrict__ o1, f16* __restrict__ o2, f16* __restrict__ o3)
{
    __shared__ f16 tile[64][72];
    int zs = blockIdx.z;
    const float* W = (zs == 0) ? w0 : (zs == 1) ? w1 : (zs == 2) ? w2 : w3;
    f16* O = (zs == 0) ? o0 : (zs == 1) ? o1 : (zs == 2) ? o2 : o3;
    int cx = blockIdx.x * 64;
    int ry = blockIdx.y * 64;
    int tid = threadIdx.x;
    #pragma unroll
    for (int p = 0; p < 4; ++p) {
        int idx = tid + p * 256;
        int r = idx >> 4, c4 = (idx & 15) << 2;
        f32x4v x = *(const f32x4v*)&W[(size_t)(ry + r) * 1024 + cx + c4];
        tile[r][c4 + 0] = (f16)x[0]; tile[r][c4 + 1] = (f16)x[1];
        tile[r][c4 + 2] = (f16)x[2]; tile[r][c4 + 3] = (f16)x[3];
    }
    __syncthreads();
    #pragma unroll
    for (int p = 0; p < 2; ++p) {
        int idx = tid + p * 256;
        int n = idx >> 3, c8 = (idx & 7) << 3;
        union { f16 h[8]; u16x8 u; } pk;
        #pragma unroll
        for (int j = 0; j < 8; ++j) pk.h[j] = tile[c8 + j][n];
        *(u16x8*)&O[(size_t)(cx + n) * 1024 + ry + c8] = pk.u;
    }
}

// ---------------------------------------------------------------------------
// GEMM core: C[m][n] = A[2048x1024] @ Bt[1024x1024]^T + bias[n]
// ---------------------------------------------------------------------------
__device__ __forceinline__ void gemm_core(
    const f16* __restrict__ A, const f16* __restrict__ Bt,
    const float* __restrict__ bias, void* __restrict__ out, int mode)
{
    __shared__ f16 As[128 * 72];
    __shared__ f16 Bs[64 * 72];
    const int mbase = blockIdx.y * 128;
    const int nbase = blockIdx.x * 64;
    int tid = threadIdx.x;
    int lane = tid & 63, wave = tid >> 6;
    int ln = lane & 15, hi = lane >> 4;
    int wr = wave & 1, wc = wave >> 1;
    v4f acc[4][2];
    #pragma unroll
    for (int rt = 0; rt < 4; ++rt)
        #pragma unroll
        for (int ct = 0; ct < 2; ++ct) acc[rt][ct] = (v4f){0.f, 0.f, 0.f, 0.f};

    for (int kb = 0; kb < 1024; kb += 64) {
        __syncthreads();
        #pragma unroll
        for (int p = 0; p < 4; ++p) {
            int idx = tid + p * 256;
            int r = idx >> 3, c8 = (idx & 7) << 3;
            *(u16x8*)&As[r * 72 + c8] = *(const u16x8*)&A[(size_t)(mbase + r) * 1024 + kb + c8];
        }
        #pragma unroll
        for (int p = 0; p < 2; ++p) {
            int idx = tid + p * 256;
            int r = idx >> 3, c8 = (idx & 7) << 3;
            *(u16x8*)&Bs[r * 72 + c8] = *(const u16x8*)&Bt[(size_t)(nbase + r) * 1024 + kb + c8];
        }
        __syncthreads();
        #pragma unroll
        for (int kk = 0; kk < 64; kk += 32) {
            half8 aF[4], bF[2];
            #pragma unroll
            for (int rt = 0; rt < 4; ++rt)
                aF[rt] = *(const half8*)&As[(wr * 64 + rt * 16 + ln) * 72 + kk + 8 * hi];
            #pragma unroll
            for (int ct = 0; ct < 2; ++ct)
                bF[ct] = *(const half8*)&Bs[(wc * 32 + ct * 16 + ln) * 72 + kk + 8 * hi];
            #pragma unroll
            for (int rt = 0; rt < 4; ++rt)
                #pragma unroll
                for (int ct = 0; ct < 2; ++ct)
                    acc[rt][ct] = __builtin_amdgcn_mfma_f32_16x16x32_f16(aF[rt], bF[ct], acc[rt][ct], 0, 0, 0);
        }
    }
    #pragma unroll
    for (int rt = 0; rt < 4; ++rt)
      #pragma unroll
      for (int ct = 0; ct < 2; ++ct)
        #pragma unroll
        for (int r = 0; r < 4; ++r) {
            int m = mbase + wr * 64 + rt * 16 + hi * 4 + r;
            int n = nbase + wc * 32 + ct * 16 + ln;
            float val = acc[rt][ct][r] + bias[n];
            if (mode == 0) {
                int bb = m >> 10, nq = m & 1023, hh = n >> 6, d = n & 63;
                ((f16*)out)[(((size_t)(bb * 16 + hh)) * 1024 + nq) * 64 + d] = (f16)val;
            } else if (mode == 1) {
                int bb = m >> 10, nq = m & 1023, hh = n >> 6, d = n & 63;
                ((f16*)out)[(((size_t)(bb * 16 + hh)) * 64 + d) * 1024 + nq] = (f16)val;
            } else {
                ((float*)out)[(size_t)m * 1024 + n] = val;
            }
        }
}

__global__ __launch_bounds__(256) void qkv_gemm_kernel(
    const f16* __restrict__ xq, const f16* __restrict__ xk, const f16* __restrict__ xv,
    const f16* __restrict__ wqt, const f16* __restrict__ wkt, const f16* __restrict__ wvt,
    const float* __restrict__ bq, const float* __restrict__ bk, const float* __restrict__ bv,
    f16* __restrict__ oQ, f16* __restrict__ oK, f16* __restrict__ oVt)
{
    int z = blockIdx.z;
    const f16* A  = (z == 0) ? xq  : (z == 1) ? xk  : xv;
    const f16* B  = (z == 0) ? wqt : (z == 1) ? wkt : wvt;
    const float* bi = (z == 0) ? bq : (z == 1) ? bk : bv;
    void* out = (z == 0) ? (void*)oQ : (z == 1) ? (void*)oK : (void*)oVt;
    gemm_core(A, B, bi, out, (z == 2) ? 1 : 0);
}

__global__ __launch_bounds__(256) void o_gemm_kernel(
    const f16* __restrict__ A, const f16* __restrict__ Wot,
    const float* __restrict__ bo, float* __restrict__ out)
{
    gemm_core(A, Wot, bo, out, 2);
}

// ---------------------------------------------------------------------------
// Split-K/2 flash attention (R7 config, consolidated best).
// WG = 512 thr (8 waves), owns (b, h, 128 q-rows, one 512-key half).
// K-half (512x64, pad 72) and V^T-half (64x512, pad 516 — lane stride 1032 B
// -> bank = 2*ln mod 32, 4-way instead of 520's 8-way) staged in LDS once;
// single barrier; barrier-free main loop with a homogeneous HBM stream
// (w/m 2-deep named register prefetch + nontemporal amap stores).
// Swapped QK^T (q = lane&15 lane-local online softmax), PV via 16x16x16
// MFMA from LDS. Partial O stored f16 (R10-15-proven), (m,l) f32.
// No min-waves in launch_bounds (R8 spill trap).
// ---------------------------------------------------------------------------
__global__ __launch_bounds__(512) void attn_kernel(
    const f16* __restrict__ Qp, const f16* __restrict__ Kp, const f16* __restrict__ Vt,
    const float* __restrict__ weights, const int* __restrict__ mask,
    float* __restrict__ amap, f16* __restrict__ Po, float* __restrict__ Ml)
{
    __shared__ f16 Ks[512 * 72];
    __shared__ f16 Vs[64 * 516];

    int h = blockIdx.x, qc = blockIdx.y, zid = blockIdx.z;
    int b = zid >> 1, kh = zid & 1;
    int bh = b * 16 + h;
    int tid = threadIdx.x;
    int lane = tid & 63, wave = tid >> 6;
    int ln = lane & 15, hi = lane >> 4;

    const f16* Kb = Kp + ((size_t)bh * 1024 + kh * 512) * 64;   // K rows of this half
    const f16* Vb = Vt + (size_t)bh * 64 * 1024 + kh * 512;     // V^T, col offset

    // ---- stage K half: 4096 16B chunks, fully contiguous in global ----
    #pragma unroll
    for (int i = 0; i < 8; ++i) {
        int c = tid + i * 512;
        int r = c >> 3, g = c & 7;
        *(half8*)&Ks[r * 72 + g * 8] = *(const half8*)&Kb[(size_t)c * 8];
    }
    // ---- stage V^T half: 64 rows x 512 cols (8B writes: rows 8B-aligned) ----
    #pragma unroll
    for (int i = 0; i < 8; ++i) {
        int c = tid + i * 512;
        int r = c >> 6, g = c & 63;
        half8 v8 = *(const half8*)&Vb[(size_t)r * 1024 + g * 8];
        half4 lo = { v8[0], v8[1], v8[2], v8[3] };
        half4 hi4 = { v8[4], v8[5], v8[6], v8[7] };
        *(half4*)&Vs[r * 516 + g * 8]     = lo;
        *(half4*)&Vs[r * 516 + g * 8 + 4] = hi4;
    }

    int qg = qc * 128 + wave * 16 + ln;                 // this lane's q row
    const f16*  Qb = Qp + ((size_t)bh * 1024 + qg) * 64;
    const float* Wr = weights + ((size_t)bh * 1024 + qg) * 1024 + kh * 512;
    const int*   Mr = mask    + ((size_t)bh * 1024 + qg) * 1024 + kh * 512;
    float*       Ar = amap    + ((size_t)bh * 1024 + qg) * 1024 + kh * 512;

    half8 qf0 = *(const half8*)&Qb[8 * hi];
    half8 qf1 = *(const half8*)&Qb[32 + 8 * hi];

    float mrun = -3.0e38f, lrun = 0.f;
    v4f oacc[4];
    #pragma unroll
    for (int dt = 0; dt < 4; ++dt) oacc[dt] = (v4f){0.f, 0.f, 0.f, 0.f};

    // 2-deep named prefetch of weights/mask (the only HBM loads in the loop)
    f32x4v wA[4], wB[4]; i32x4 mA[4], mB[4];
    #pragma unroll
    for (int t = 0; t < 4; ++t) {
        wA[t] = *(const f32x4v*)&Wr[t * 16 + 4 * hi];
        mA[t] = *(const i32x4*)&Mr[t * 16 + 4 * hi];
        wB[t] = *(const f32x4v*)&Wr[64 + t * 16 + 4 * hi];
        mB[t] = *(const i32x4*)&Mr[64 + t * 16 + 4 * hi];
    }
    __syncthreads();   // LDS staged; read-only from here, no more barriers

    auto process = [&](int kt, const f32x4v (&wb)[4], const i32x4 (&mb)[4]) {
        // ---- S^T = K Q^T from LDS ----
        v4f st[4];
        #pragma unroll
        for (int t = 0; t < 4; ++t) {
            const f16* kr = &Ks[(kt * 64 + t * 16 + ln) * 72 + 8 * hi];
            half8 ka = *(const half8*)kr;
            half8 kc = *(const half8*)(kr + 32);
            v4f a = (v4f){0.f, 0.f, 0.f, 0.f};
            a = MFMA32(ka, qf0, a);
            a = MFMA32(kc, qf1, a);
            st[t] = a;
        }
        // ---- amap (nontemporal) + z ----
        float z[4][4];
        #pragma unroll
        for (int t = 0; t < 4; ++t) {
            f32x4v sv = st[t] * 0.125f;
            __builtin_nontemporal_store(sv, (f32x4v*)&Ar[kt * 64 + t * 16 + 4 * hi]);
            #pragma unroll
            for (int r = 0; r < 4; ++r)
                z[t][r] = (mb[t][r] == 0) ? NEG_BIG : sv[r] * wb[t][r];
        }
        // ---- online softmax (q lane-local; reduce across hi groups) ----
        float tm = z[0][0];
        #pragma unroll
        for (int t = 0; t < 4; ++t)
            #pragma unroll
            for (int r = 0; r < 4; ++r) tm = fmaxf(tm, z[t][r]);
        tm = fmaxf(tm, __shfl_xor(tm, 16, 64));
        tm = fmaxf(tm, __shfl_xor(tm, 32, 64));
        float mnew = fmaxf(mrun, tm);
        float fsc = __expf(mrun - mnew);
        float p[4][4];
        float tsum = 0.f;
        #pragma unroll
        for (int t = 0; t < 4; ++t)
            #pragma unroll
            for (int r = 0; r < 4; ++r) { p[t][r] = __expf(z[t][r] - mnew); tsum += p[t][r]; }
        tsum += __shfl_xor(tsum, 16, 64);
        tsum += __shfl_xor(tsum, 32, 64);
        lrun = lrun * fsc + tsum;
        mrun = mnew;
        #pragma unroll
        for (int dt = 0; dt < 4; ++dt) oacc[dt] *= fsc;
        // ---- P^T f16 fragments (K=16 layout k = 4*hi + j) ----
        half4 pf[4];
        #pragma unroll
        for (int t = 0; t < 4; ++t) {
            half4 v;
            v[0] = (f16)p[t][0]; v[1] = (f16)p[t][1];
            v[2] = (f16)p[t][2]; v[3] = (f16)p[t][3];
            pf[t] = v;
        }
        // ---- O^T += V^T P^T from LDS ----
        #pragma unroll
        for (int t = 0; t < 4; ++t)
            #pragma unroll
            for (int dt = 0; dt < 4; ++dt) {
                half4 vf = *(const half4*)&Vs[(dt * 16 + ln) * 516 + kt * 64 + t * 16 + 4 * hi];
                oacc[dt] = MFMA16(vf, pf[t], oacc[dt]);
            }
    };

    #pragma unroll 1
    for (int kt2 = 0; kt2 < 4; ++kt2) {
        int kt = kt2 * 2;
        process(kt, wA, mA);
        if (kt2 < 3) {
            #pragma unroll
            for (int t = 0; t < 4; ++t) {
                wA[t] = *(const f32x4v*)&Wr[(kt + 2) * 64 + t * 16 + 4 * hi];
                mA[t] = *(const i32x4*)&Mr[(kt + 2) * 64 + t * 16 + 4 * hi];
            }
        }
        process(kt + 1, wB, mB);
        if (kt2 < 3) {
            #pragma unroll
            for (int t = 0; t < 4; ++t) {
                wB[t] = *(const f32x4v*)&Wr[(kt + 3) * 64 + t * 16 + 4 * hi];
                mB[t] = *(const i32x4*)&Mr[(kt + 3) * 64 + t * 16 + 4 * hi];
            }
        }
    }

    // ---- epilogue: store unnormalized partial O (f16) + (m, l) ----
    size_t prow = ((size_t)kh * 32 + bh) * 1024 + qg;
    #pragma unroll
    for (int dt = 0; dt < 4; ++dt) {
        half4 ov;
        #pragma unroll
        for (int r = 0; r < 4; ++r) ov[r] = (f16)oacc[dt][r];
        *(half4*)&Po[prow * 64 + dt * 16 + 4 * hi] = ov;
    }
    if (hi == 0) {
        float2 ml = make_float2(mrun, lrun);
        *(float2*)&Ml[prow * 2] = ml;
    }
}

// ---------------------------------------------------------------------------
// Merge the two k-half partials: O = (w0*O0 + w1*O1) / (w0*l0 + w1*l1)
// ---------------------------------------------------------------------------
__global__ __launch_bounds__(256) void merge_kernel(
    const f16* __restrict__ Po, const float* __restrict__ Ml, f16* __restrict__ hout)
{
    int gid = blockIdx.x * 256 + threadIdx.x;
    int dq = gid & 15;
    int q  = (gid >> 4) & 1023;
    int bh = gid >> 14;
    int b = bh >> 4, h = bh & 15;
    size_t r0 = (size_t)bh * 1024 + q;
    size_t r1 = (size_t)(32 + bh) * 1024 + q;
    float2 ml0 = *(const float2*)&Ml[r0 * 2];
    float2 ml1 = *(const float2*)&Ml[r1 * 2];
    float M = fmaxf(ml0.x, ml1.x);
    float w0 = __expf(ml0.x - M), w1 = __expf(ml1.x - M);
    float rL = 1.0f / (w0 * ml0.y + w1 * ml1.y);
    half4 o0 = *(const half4*)&Po[r0 * 64 + dq * 4];
    half4 o1 = *(const half4*)&Po[r1 * 64 + dq * 4];
    half4 ov;
    #pragma unroll
    for (int j = 0; j < 4; ++j)
        ov[j] = (f16)((w0 * (float)o0[j] + w1 * (float)o1[j]) * rL);
    *(half4*)&hout[((size_t)(b * 1024 + q)) * 1024 + h * 64 + dq * 4] = ov;
}

// ---------------------------------------------------------------------------
extern "C" void kernel_launch(void* const* d_in, const int* in_sizes, int n_in,
                              void* d_out, int out_size, void* d_ws, size_t ws_size,
                              hipStream_t stream)
{
    const float* queries  = (const float*)d_in[0];
    const float* keys     = (const float*)d_in[1];
    const float* values   = (const float*)d_in[2];
    const int*   amask    = (const int*)d_in[3];
    const float* aweights = (const float*)d_in[4];
    const float* Wq = (const float*)d_in[5];  const float* bq = (const float*)d_in[6];
    const float* Wk = (const float*)d_in[7];  const float* bk = (const float*)d_in[8];
    const float* Wv = (const float*)d_in[9];  const float* bv = (const float*)d_in[10];
    const float* Wo = (const float*)d_in[11]; const float* bo = (const float*)d_in[12];

    char* ws = (char*)d_ws;
    const size_t MB = 1024 * 1024;
    f16* q_h  = (f16*)(ws + 0 * MB);
    f16* k_h  = (f16*)(ws + 4 * MB);
    f16* v_h  = (f16*)(ws + 8 * MB);
    f16* wqt  = (f16*)(ws + 12 * MB);
    f16* wkt  = (f16*)(ws + 14 * MB);
    f16* wvt  = (f16*)(ws + 16 * MB);
    f16* wot  = (f16*)(ws + 18 * MB);
    f16* Qp   = (f16*)(ws + 20 * MB);
    f16* Kp   = (f16*)(ws + 24 * MB);
    f16* Vt   = (f16*)(ws + 28 * MB);
    f16* hout = (f16*)(ws + 32 * MB);
    // Po/Ml reuse 0..17 MB (q_h/k_h/v_h/wqt/wkt dead after qkv_gemm; wot@18 safe)
    f16*   Po = (f16*)(ws + 0 * MB);       // 8 MB: 2 x 32 x 1024 x 64 f16
    float* Ml = (float*)(ws + 16 * MB);    // 512 KB: 2 x 32 x 1024 x 2 f32

    float* out_main = (float*)d_out;
    float* att_map  = out_main + (size_t)2 * 1024 * 1024;

    cvt3_kernel<<<6144, 256, 0, stream>>>(queries, keys, values, q_h, k_h, v_h);
    wtrans_kernel<<<dim3(16, 16, 4), 256, 0, stream>>>(Wq, Wk, Wv, Wo, wqt, wkt, wvt, wot);
    qkv_gemm_kernel<<<dim3(16, 16, 3), 256, 0, stream>>>(q_h, k_h, v_h, wqt, wkt, wvt,
                                                         bq, bk, bv, Qp, Kp, Vt);
    attn_kernel<<<dim3(16, 8, 4), 512, 0, stream>>>(Qp, Kp, Vt, aweights, amask,
                                                    att_map, Po, Ml);
    merge_kernel<<<2048, 256, 0, stream>>>(Po, Ml, hout);
    o_gemm_kernel<<<dim3(16, 16, 1), 256, 0, stream>>>(hout, wot, bo, out_main);
}